// Round 2
// baseline (712.680 us; speedup 1.0000x reference)
//
#include <hip/hip_runtime.h>
#include <hip/hip_bf16.h>

// Problem constants (reference: T=1024, B=16, H=1024, V=100, L=3)
#define T_DIM 1024
#define B_DIM 16
#define H_DIM 1024
#define L_DIM 3
#define M_DIM (T_DIM * B_DIM)   // 16384 rows (t*B+b)
#define N_DIM (3 * H_DIM)       // 3072 gate cols
#define K_DIM H_DIM             // 1024 reduction
#define NC 16                   // scan chunks
#define CS 64                   // chunk size (T/NC)

typedef __bf16 bf16x8 __attribute__((ext_vector_type(8)));
typedef float f32x4 __attribute__((ext_vector_type(4)));

__device__ __forceinline__ __bf16 f2bf(float f) {
    return (__bf16)__float2bfloat16(f);   // RNE convert
}

// async global->LDS, 16B per lane. LDS dest is wave-uniform base + lane*16.
__device__ __forceinline__ void async_cp16(const void* g, void* lds) {
    __builtin_amdgcn_global_load_lds(
        (__attribute__((address_space(1))) void*)g,
        (__attribute__((address_space(3))) void*)lds, 16, 0, 0);
}

// ---------------- W transpose+cast: W[l][k][n] fp32 -> Wt[l][n][k] bf16 ----------------
__global__ void transpose_w(const float* __restrict__ W,
                            __bf16* __restrict__ Wt) {
    __shared__ __bf16 tile[32][33];   // +1 pad: no bank conflicts
    const int l = blockIdx.z;
    const int k0 = blockIdx.x * 32, n0 = blockIdx.y * 32;
    const int tx = threadIdx.x & 31, ty = threadIdx.x >> 5;  // ty in 0..7
    const float* Wl = W + (size_t)l * K_DIM * N_DIM;
    __bf16* Wtl = Wt + (size_t)l * N_DIM * K_DIM;
#pragma unroll
    for (int q = 0; q < 4; q++) {
        int k = ty + q * 8;
        tile[k][tx] = f2bf(Wl[(size_t)(k0 + k) * N_DIM + n0 + tx]);
    }
    __syncthreads();
#pragma unroll
    for (int q = 0; q < 4; q++) {
        int n = ty + q * 8;
        Wtl[(size_t)(n0 + n) * K_DIM + k0 + tx] = tile[tx][n];
    }
}

// ---------------- embedding gather+cast: h[t*B+b][:] = bf16(emb[x[t*B+b]][:]) ----------------
__global__ void embed_kernel(const int* __restrict__ x,
                             const float4* __restrict__ emb,   // rows of 256 float4
                             __bf16* __restrict__ h) {
    int i = blockIdx.x * 256 + threadIdx.x;   // M*H/4 threads
    int row = i >> 8;                         // H/4 = 256 chunks per row
    int j = i & 255;
    int idx = x[row];
    float4 v = emb[(size_t)idx * 256 + j];
    __bf16* dst = h + (size_t)row * H_DIM + j * 4;
    dst[0] = f2bf(v.x); dst[1] = f2bf(v.y); dst[2] = f2bf(v.z); dst[3] = f2bf(v.w);
}

// ---------------- GEMM + bias + activation -> fp32 gates ----------------
// A [M,K] bf16 row-major (h), Wt [N,K] bf16 row-major, G [M,N] fp32.
// 128x128 tile, BK=32, 4 waves in 2x2, each wave 4x4 frags of 16x16x32 MFMA.
__global__ __launch_bounds__(256, 2) void gemm_gates(
    const __bf16* __restrict__ A,
    const __bf16* __restrict__ Wt,
    const float* __restrict__ bias,
    float* __restrict__ G) {
    __shared__ __align__(16) __bf16 As[128 * 32];
    __shared__ __align__(16) __bf16 Bs[128 * 32];

    const int tid = threadIdx.x;
    const int wid = tid >> 6, lane = tid & 63;
    const int bm = blockIdx.x, bn = blockIdx.y;
    const int waveM = wid >> 1, waveN = wid & 1;
    const int lm = lane & 15, kg = lane >> 4;   // frag row, k-group

    // staging: 512 cells of 8 bf16; cell c -> tile row c>>2, col (c&3)*8
    const int r0 = tid >> 2, cc = (tid & 3) * 8;
    const int r1 = r0 + 64;
    const __bf16* Abase = A + (size_t)(bm * 128) * K_DIM;
    const __bf16* Bbase = Wt + (size_t)(bn * 128) * K_DIM;
    // wave-uniform LDS destinations (lane scatter is +lane*16B)
    __bf16* ldsA0 = As + (size_t)(wid * 64) * 8;
    __bf16* ldsA1 = As + (size_t)(wid * 64 + 256) * 8;
    __bf16* ldsB0 = Bs + (size_t)(wid * 64) * 8;
    __bf16* ldsB1 = Bs + (size_t)(wid * 64 + 256) * 8;

    f32x4 acc[4][4] = {};

    for (int k0 = 0; k0 < K_DIM; k0 += 32) {
        async_cp16(Abase + (size_t)r0 * K_DIM + k0 + cc, ldsA0);
        async_cp16(Abase + (size_t)r1 * K_DIM + k0 + cc, ldsA1);
        async_cp16(Bbase + (size_t)r0 * K_DIM + k0 + cc, ldsB0);
        async_cp16(Bbase + (size_t)r1 * K_DIM + k0 + cc, ldsB1);
        __syncthreads();   // drains vmcnt before barrier

        bf16x8 af[4], bf[4];
#pragma unroll
        for (int i = 0; i < 4; i++)
            af[i] = *(const bf16x8*)(As + (waveM * 64 + i * 16 + lm) * 32 + kg * 8);
#pragma unroll
        for (int j = 0; j < 4; j++)
            bf[j] = *(const bf16x8*)(Bs + (waveN * 64 + j * 16 + lm) * 32 + kg * 8);
#pragma unroll
        for (int i = 0; i < 4; i++)
#pragma unroll
            for (int j = 0; j < 4; j++)
                acc[i][j] = __builtin_amdgcn_mfma_f32_16x16x32_bf16(af[i], bf[j], acc[i][j], 0, 0, 0);
        __syncthreads();
    }

    // epilogue: bias + activation, store fp32 gates.
    // C/D layout: col = lane&15, row = (lane>>4)*4 + reg  [m89-verified]
#pragma unroll
    for (int i = 0; i < 4; i++) {
#pragma unroll
        for (int j = 0; j < 4; j++) {
            int ncol = bn * 128 + waveN * 64 + j * 16 + lm;
            float bv = bias[ncol];
            int gate = ncol >> 10;   // 0=z(tanh) 1=f(sig) 2=o(sig)
#pragma unroll
            for (int r = 0; r < 4; r++) {
                int mrow = bm * 128 + waveM * 64 + i * 16 + kg * 4 + r;
                float g = acc[i][j][r] + bv;
                float val;
                if (gate == 0) {
                    // overflow-safe tanh: e = exp(-2|g|) <= 1
                    float e = __expf(-2.0f * fabsf(g));
                    val = copysignf((1.0f - e) / (1.0f + e), g);
                } else {
                    val = 1.0f / (1.0f + __expf(-g));    // saturates safely
                }
                G[(size_t)mrow * N_DIM + ncol] = val;
            }
        }
    }
}

// ---------------- scan pass 1: per-chunk affine aggregates ----------------
// c_out = Aagg + Magg * c_in over a 64-step chunk.
__global__ void scan_pass1(const float* __restrict__ G,
                           float* __restrict__ cA, float* __restrict__ cM) {
    int tidg = blockIdx.x * 256 + threadIdx.x;   // NC * B*H = 262144
    int ci = tidg >> 14;
    int ch = tidg & 16383;
    int b = ch >> 10, h = ch & 1023;
    float Aacc = 0.f, Macc = 1.f;
    const float* base = G + (size_t)((ci * CS * B_DIM + b) * N_DIM) + h;
#pragma unroll 8
    for (int s = 0; s < CS; s++) {
        float z = base[0];
        float f = base[1024];
        Aacc = f * z + (1.f - f) * Aacc;
        Macc = (1.f - f) * Macc;
        base += B_DIM * N_DIM;
    }
    cA[tidg] = Aacc;
    cM[tidg] = Macc;
}

// ---------------- scan pass 2: scan across 16 chunks ----------------
__global__ void scan_pass2(const float* __restrict__ cA, const float* __restrict__ cM,
                           float* __restrict__ cIn) {
    int ch = blockIdx.x * 256 + threadIdx.x;   // 16384
    float c = 0.f;
#pragma unroll
    for (int ci = 0; ci < NC; ci++) {
        cIn[ci * 16384 + ch] = c;
        c = cA[ci * 16384 + ch] + cM[ci * 16384 + ch] * c;
    }
}

// ---------------- scan pass 3: rescan + output gate ----------------
// not-last: write bf16 h for next GEMM.  last: write fp32 to d_out, drop t=T-1.
__global__ void scan_pass3(const float* __restrict__ G, const float* __restrict__ cIn,
                           __bf16* __restrict__ hdst, float* __restrict__ fdst,
                           int is_last) {
    int tidg = blockIdx.x * 256 + threadIdx.x;
    int ci = tidg >> 14;
    int ch = tidg & 16383;
    int b = ch >> 10, h = ch & 1023;
    float c = cIn[tidg];
    const float* base = G + (size_t)((ci * CS * B_DIM + b) * N_DIM) + h;
#pragma unroll 4
    for (int s = 0; s < CS; s++) {
        int t = ci * CS + s;
        float z = base[0];
        float f = base[1024];
        float o = base[2048];
        c = f * z + (1.f - f) * c;
        float val = o * c;
        base += B_DIM * N_DIM;
        size_t oi = (size_t)(t * B_DIM + b) * H_DIM + h;
        if (is_last) {
            if (t < T_DIM - 1) fdst[oi] = val;
        } else {
            hdst[oi] = f2bf(val);
        }
    }
}

extern "C" void kernel_launch(void* const* d_in, const int* in_sizes, int n_in,
                              void* d_out, int out_size, void* d_ws, size_t ws_size,
                              hipStream_t stream) {
    const int* x = (const int*)d_in[0];          // [T,B] int32
    const float* emb = (const float*)d_in[1];    // [V,H] fp32
    const float* W = (const float*)d_in[2];      // [L,H,3H] fp32
    const float* b = (const float*)d_in[3];      // [L,3H] fp32
    float* out = (float*)d_out;                  // [T-1,B,H] fp32

    // workspace layout
    char* ws = (char*)d_ws;
    size_t need = (size_t)L_DIM * N_DIM * K_DIM * 2   // Wt (bf16)
                + (size_t)M_DIM * H_DIM * 2           // hbuf (bf16)
                + (size_t)M_DIM * N_DIM * 4           // gates (fp32)
                + 3ull * NC * 16384 * 4;              // chunk aggregates
    if (ws_size < need) return;   // fail visibly rather than corrupt

    __bf16* Wt = (__bf16*)ws;   ws += (size_t)L_DIM * N_DIM * K_DIM * 2;
    __bf16* hbuf = (__bf16*)ws; ws += (size_t)M_DIM * H_DIM * 2;
    float* gates = (float*)ws;  ws += (size_t)M_DIM * N_DIM * 4;
    float* cA = (float*)ws;     ws += (size_t)NC * 16384 * 4;
    float* cM = (float*)ws;     ws += (size_t)NC * 16384 * 4;
    float* cIn = (float*)ws;

    transpose_w<<<dim3(K_DIM / 32, N_DIM / 32, L_DIM), 256, 0, stream>>>(W, Wt);
    embed_kernel<<<(M_DIM * H_DIM / 4) / 256, 256, 0, stream>>>(x, (const float4*)emb, hbuf);

    for (int l = 0; l < L_DIM; l++) {
        gemm_gates<<<dim3(M_DIM / 128, N_DIM / 128), 256, 0, stream>>>(
            hbuf, Wt + (size_t)l * N_DIM * K_DIM, b + (size_t)l * N_DIM, gates);
        scan_pass1<<<(NC * 16384) / 256, 256, 0, stream>>>(gates, cA, cM);
        scan_pass2<<<16384 / 256, 256, 0, stream>>>(cA, cM, cIn);
        int last = (l == L_DIM - 1);
        scan_pass3<<<(NC * 16384) / 256, 256, 0, stream>>>(
            gates, cIn, hbuf, out, last);
    }
}

// Round 3
// 639.711 us; speedup vs baseline: 1.1141x; 1.1141x over previous
//
#include <hip/hip_runtime.h>
#include <hip/hip_bf16.h>

#define T_DIM 1024
#define B_DIM 16
#define H_DIM 1024
#define L_DIM 3
#define M_DIM (T_DIM * B_DIM)
#define N_DIM (3 * H_DIM)
#define K_DIM H_DIM
#define NC 32
#define CS 32

typedef __bf16 bf16x8 __attribute__((ext_vector_type(8)));
typedef __bf16 bf16x4 __attribute__((ext_vector_type(4)));
typedef _Float16 half4 __attribute__((ext_vector_type(4)));
typedef float f32x4 __attribute__((ext_vector_type(4)));

__device__ __forceinline__ __bf16 f2bf(float f) {
    return (__bf16)__float2bfloat16(f);
}

__device__ __forceinline__ void async_cp16(const void* g, void* lds) {
    __builtin_amdgcn_global_load_lds(
        (__attribute__((address_space(1))) void*)g,
        (__attribute__((address_space(3))) void*)lds, 16, 0, 0);
}

__global__ void transpose_w(const float* __restrict__ W, __bf16* __restrict__ Wt) {
    __shared__ __bf16 tile[32][33];
    const int l = blockIdx.z;
    const int k0 = blockIdx.x * 32, n0 = blockIdx.y * 32;
    const int tx = threadIdx.x & 31, ty = threadIdx.x >> 5;
    const float* Wl = W + (size_t)l * K_DIM * N_DIM;
    __bf16* Wtl = Wt + (size_t)l * N_DIM * K_DIM;
#pragma unroll
    for (int q = 0; q < 4; q++) {
        int k = ty + q * 8;
        tile[k][tx] = f2bf(Wl[(size_t)(k0 + k) * N_DIM + n0 + tx]);
    }
    __syncthreads();
#pragma unroll
    for (int q = 0; q < 4; q++) {
        int n = ty + q * 8;
        Wtl[(size_t)(n0 + n) * K_DIM + k0 + tx] = tile[tx][n];
    }
}

__global__ void embed_kernel(const int* __restrict__ x,
                             const float4* __restrict__ emb,
                             __bf16* __restrict__ h) {
    int i = blockIdx.x * 256 + threadIdx.x;
    int row = i >> 8;
    int j = i & 255;
    int idx = x[row];
    float4 v = emb[(size_t)idx * 256 + j];
    __bf16* dst = h + (size_t)row * H_DIM + j * 4;
    dst[0] = f2bf(v.x); dst[1] = f2bf(v.y); dst[2] = f2bf(v.z); dst[3] = f2bf(v.w);
}

// GEMM + bias + activation -> fp16 planar gates. XOR-swizzled LDS (slot = c ^ ((r>>1)&3)).
__global__ __launch_bounds__(256, 2) void gemm_gates(
    const __bf16* __restrict__ A,
    const __bf16* __restrict__ Wt,
    const float* __restrict__ bias,
    _Float16* __restrict__ Gz, _Float16* __restrict__ Gf, _Float16* __restrict__ Go) {
    __shared__ __align__(16) __bf16 As[128 * 32];
    __shared__ __align__(16) __bf16 Bs[128 * 32];

    const int tid = threadIdx.x;
    const int wid = tid >> 6, lane = tid & 63;
    const int bm = blockIdx.x, bn = blockIdx.y;
    const int waveM = wid >> 1, waveN = wid & 1;
    const int lm = lane & 15, kg = lane >> 4;

    const int r0 = tid >> 2;
    const int cc = (((tid & 3) ^ ((r0 >> 1) & 3))) * 8;  // swizzled global chunk (elems)
    const int r1 = r0 + 64;                              // (r1>>1)&3 == (r0>>1)&3
    const __bf16* Abase = A + (size_t)(bm * 128) * K_DIM;
    const __bf16* Bbase = Wt + (size_t)(bn * 128) * K_DIM;
    __bf16* ldsA0 = As + (size_t)wid * 512;
    __bf16* ldsA1 = As + (size_t)wid * 512 + 2048;
    __bf16* ldsB0 = Bs + (size_t)wid * 512;
    __bf16* ldsB1 = Bs + (size_t)wid * 512 + 2048;

    const int csw = (kg ^ ((lm >> 1) & 3)) * 8;          // swizzled read chunk (elems)

    f32x4 acc[4][4] = {};

    for (int k0 = 0; k0 < K_DIM; k0 += 32) {
        async_cp16(Abase + (size_t)r0 * K_DIM + k0 + cc, ldsA0);
        async_cp16(Abase + (size_t)r1 * K_DIM + k0 + cc, ldsA1);
        async_cp16(Bbase + (size_t)r0 * K_DIM + k0 + cc, ldsB0);
        async_cp16(Bbase + (size_t)r1 * K_DIM + k0 + cc, ldsB1);
        __syncthreads();

        bf16x8 af[4], bf[4];
#pragma unroll
        for (int i = 0; i < 4; i++)
            af[i] = *(const bf16x8*)(As + (waveM * 64 + i * 16 + lm) * 32 + csw);
#pragma unroll
        for (int j = 0; j < 4; j++)
            bf[j] = *(const bf16x8*)(Bs + (waveN * 64 + j * 16 + lm) * 32 + csw);
#pragma unroll
        for (int i = 0; i < 4; i++)
#pragma unroll
            for (int j = 0; j < 4; j++)
                acc[i][j] = __builtin_amdgcn_mfma_f32_16x16x32_bf16(af[i], bf[j], acc[i][j], 0, 0, 0);
        __syncthreads();
    }

    // epilogue; plane is block-uniform (bn covers 128 cols inside one 1024-col plane)
    const int plane = bn >> 3;
    _Float16* __restrict__ P = (plane == 0) ? Gz : (plane == 1) ? Gf : Go;
#pragma unroll
    for (int i = 0; i < 4; i++) {
#pragma unroll
        for (int j = 0; j < 4; j++) {
            int ncol = bn * 128 + waveN * 64 + j * 16 + lm;
            int col = ncol & 1023;
            float bv = bias[ncol];
#pragma unroll
            for (int r = 0; r < 4; r++) {
                int mrow = bm * 128 + waveM * 64 + i * 16 + kg * 4 + r;
                float g = acc[i][j][r] + bv;
                float val;
                if (plane == 0) {
                    float e = __expf(-2.0f * fabsf(g));
                    val = copysignf((1.0f - e) / (1.0f + e), g);
                } else {
                    val = 1.0f / (1.0f + __expf(-g));
                }
                P[(size_t)mrow * H_DIM + col] = (_Float16)val;
            }
        }
    }
}

__global__ void scan_pass1(const _Float16* __restrict__ Gz, const _Float16* __restrict__ Gf,
                           float* __restrict__ cA, float* __restrict__ cM) {
    int tid = blockIdx.x * 256 + threadIdx.x;   // 131072
    int ci = tid >> 12;
    int b = (tid >> 8) & 15;
    int hg = tid & 255;
    size_t base = ((size_t)(ci * CS) * B_DIM + b) * H_DIM + hg * 4;
    f32x4 Aacc = {0.f, 0.f, 0.f, 0.f};
    f32x4 Macc = {1.f, 1.f, 1.f, 1.f};
#pragma unroll 8
    for (int s = 0; s < CS; s++) {
        half4 z = *(const half4*)(Gz + base);
        half4 f = *(const half4*)(Gf + base);
#pragma unroll
        for (int k = 0; k < 4; k++) {
            float fk = (float)f[k], zk = (float)z[k];
            Aacc[k] = fk * zk + (1.f - fk) * Aacc[k];
            Macc[k] = (1.f - fk) * Macc[k];
        }
        base += (size_t)B_DIM * H_DIM;
    }
    size_t idx = (size_t)ci * 16384 + 4 * (size_t)(tid & 4095);
    *(f32x4*)(cA + idx) = Aacc;
    *(f32x4*)(cM + idx) = Macc;
}

__global__ void scan_pass2(const float* __restrict__ cA, const float* __restrict__ cM,
                           float* __restrict__ cIn) {
    int ch = blockIdx.x * 256 + threadIdx.x;   // 16384
    float c = 0.f;
#pragma unroll
    for (int ci = 0; ci < NC; ci++) {
        cIn[ci * 16384 + ch] = c;
        c = cA[ci * 16384 + ch] + cM[ci * 16384 + ch] * c;
    }
}

__global__ void scan_pass3(const _Float16* __restrict__ Gz, const _Float16* __restrict__ Gf,
                           const _Float16* __restrict__ Go, const float* __restrict__ cIn,
                           __bf16* __restrict__ hdst, float* __restrict__ fdst,
                           int is_last) {
    int tid = blockIdx.x * 256 + threadIdx.x;   // 131072
    int ci = tid >> 12;
    int b = (tid >> 8) & 15;
    int hg = tid & 255;
    size_t base = ((size_t)(ci * CS) * B_DIM + b) * H_DIM + hg * 4;
    f32x4 c = *(const f32x4*)(cIn + (size_t)ci * 16384 + 4 * (size_t)(tid & 4095));
#pragma unroll 4
    for (int s = 0; s < CS; s++) {
        int t = ci * CS + s;
        half4 z = *(const half4*)(Gz + base);
        half4 f = *(const half4*)(Gf + base);
        half4 o = *(const half4*)(Go + base);
        f32x4 val;
#pragma unroll
        for (int k = 0; k < 4; k++) {
            float fk = (float)f[k];
            c[k] = fk * (float)z[k] + (1.f - fk) * c[k];
            val[k] = (float)o[k] * c[k];
        }
        if (is_last) {
            if (t < T_DIM - 1)
                *(f32x4*)(fdst + base) = val;
        } else {
            bf16x4 hv;
#pragma unroll
            for (int k = 0; k < 4; k++) hv[k] = f2bf(val[k]);
            *(bf16x4*)(hdst + base) = hv;
        }
        base += (size_t)B_DIM * H_DIM;
    }
}

extern "C" void kernel_launch(void* const* d_in, const int* in_sizes, int n_in,
                              void* d_out, int out_size, void* d_ws, size_t ws_size,
                              hipStream_t stream) {
    const int* x = (const int*)d_in[0];
    const float* emb = (const float*)d_in[1];
    const float* W = (const float*)d_in[2];
    const float* b = (const float*)d_in[3];
    float* out = (float*)d_out;

    char* ws = (char*)d_ws;
    size_t need = (size_t)L_DIM * N_DIM * K_DIM * 2
                + (size_t)M_DIM * H_DIM * 2
                + 3ull * M_DIM * H_DIM * 2
                + 3ull * NC * 16384 * 4;
    if (ws_size < need) return;

    __bf16* Wt = (__bf16*)ws;     ws += (size_t)L_DIM * N_DIM * K_DIM * 2;
    __bf16* hbuf = (__bf16*)ws;   ws += (size_t)M_DIM * H_DIM * 2;
    _Float16* Gz = (_Float16*)ws; ws += (size_t)M_DIM * H_DIM * 2;
    _Float16* Gf = (_Float16*)ws; ws += (size_t)M_DIM * H_DIM * 2;
    _Float16* Go = (_Float16*)ws; ws += (size_t)M_DIM * H_DIM * 2;
    float* cA = (float*)ws;       ws += (size_t)NC * 16384 * 4;
    float* cM = (float*)ws;       ws += (size_t)NC * 16384 * 4;
    float* cIn = (float*)ws;

    transpose_w<<<dim3(K_DIM / 32, N_DIM / 32, L_DIM), 256, 0, stream>>>(W, Wt);
    embed_kernel<<<(M_DIM * H_DIM / 4) / 256, 256, 0, stream>>>(x, (const float4*)emb, hbuf);

    for (int l = 0; l < L_DIM; l++) {
        gemm_gates<<<dim3(M_DIM / 128, N_DIM / 128), 256, 0, stream>>>(
            hbuf, Wt + (size_t)l * N_DIM * K_DIM, b + (size_t)l * N_DIM, Gz, Gf, Go);
        scan_pass1<<<131072 / 256, 256, 0, stream>>>(Gz, Gf, cA, cM);
        scan_pass2<<<16384 / 256, 256, 0, stream>>>(cA, cM, cIn);
        int last = (l == L_DIM - 1);
        scan_pass3<<<131072 / 256, 256, 0, stream>>>(Gz, Gf, Go, cIn, hbuf, out, last);
    }
}